// Round 8
// baseline (15.893 us; speedup 1.0000x reference)
//
#include <hip/hip_runtime.h>

#define NPART 512
#define BATCH 128
#define MAGIC 0x5F3759DFu

// Quad-split LDS layout: particle p -> region (p&3), slot (p>>2).
// Regions are 192 float4 each (particles mirrored to p<768: slot(p+512)=slot(p)+128).
// Window reads are stride-1 float4 across lanes (conflict-free ds_read_b128),
// with compile-time immediate offsets under full unroll.
//
// grid = 256 blocks = (batch b, half s). block = 1024 threads = (t in [0,128)) x (h in [0,8)).
// Thread (t,h,s): rows i = 4t+r (r=0..3), K in [16X+1, 16X+16], X = 8s+h in [0,16).
// Each unordered pair with circular distance d<256 counted once; d=256 counted
// twice at full weight, corrected by -0.5 in the X==15 threads.
//
// Fused finish (all-RELAXED device-scope atomics, no release/acquire fences —
// R5 showed rel/acq agent-scope = L2 writeback/invalidate sweeps, +6us):
//   publish partial via atomicExch; flag-exch operand data-depends on the
//   publish's return (forces vmcnt completion order); the later block sees
//   MAGIC, reads sibling partial (address data-depends on flag return),
//   writes out[b], resets flag. Poison 0xAA != MAGIC and exchange semantics
//   make every replay pick exactly one finisher; flag self-resets.

__global__ __launch_bounds__(1024, 4) void lj_fused(
    const float* __restrict__ x, float* __restrict__ out,
    float* __restrict__ wsp, unsigned int* __restrict__ done) {
    const int bid = blockIdx.x;
    const int b = bid >> 1;
    const int s = bid & 1;
    const int tid = threadIdx.x;
    const int t = tid & 127;
    const int h = tid >> 7;

    __shared__ float4 sp[768];       // 4 regions x 192 float4 = 12 KB
    __shared__ float wred[16];
    __shared__ float wspr[2][4];

    // ---- stage 1536 floats (+768 mirror floats) into quad-split layout ----
    const float* xb = x + (size_t)b * (NPART * 3);
    float* spf = reinterpret_cast<float*>(sp);
    {
        const int idx = tid;                 // 0..1023
        const float v = xb[idx];
        const int p = idx / 3;
        const int c = idx - 3 * p;
        const int sl = (p & 3) * 192 + (p >> 2);
        spf[4 * sl + c] = v;
        if (p < 256) spf[4 * (sl + 128) + c] = v;   // mirror p+512
    }
    if (tid < 512) {
        const int idx = tid + 1024;          // 1024..1535 (p >= 341, no mirror)
        const float v = xb[idx];
        const int p = idx / 3;
        const int c = idx - 3 * p;
        const int sl = (p & 3) * 192 + (p >> 2);
        spf[4 * sl + c] = v;
    }
    __syncthreads();

    // region pointers at slot t
    const float4* R0 = sp + t;
    const float4* R1 = sp + 192 + t;
    const float4* R2 = sp + 384 + t;
    const float4* R3 = sp + 576 + t;

    const float4 pi0 = R0[0];   // particle 4t
    const float4 pi1 = R1[0];   // particle 4t+1
    const float4 pi2 = R2[0];   // particle 4t+2
    const float4 pi3 = R3[0];   // particle 4t+3

    const int X = 8 * s + h;     // 0..15 ; k0 = 16X+1 ; J = 4t + k0
    const int B4 = 4 * X;        // window slot offset (J>>2 = t + 4X)

    float accA = 0.0f, accB = 0.0f;

    // acc += i6*(i6-1) ; pot = 4*acc
    #define PT(PI, W, ACC) do {                                   \
        const float dx_ = (PI).x - (W).x;                         \
        const float dy_ = (PI).y - (W).y;                         \
        const float dz_ = (PI).z - (W).z;                         \
        const float r2_ = fmaf(dx_, dx_, fmaf(dy_, dy_, dz_ * dz_)); \
        const float i2_ = __builtin_amdgcn_rcpf(r2_);             \
        const float i6_ = i2_ * i2_ * i2_;                        \
        ACC = fmaf(i6_, i6_ - 1.0f, ACC);                         \
    } while (0)

    // sliding window w[m] holds particle j = J + m  (J = 4t + 16X + 1)
    float4 w[19];
    w[0] = R1[B4];               // j = J   : region 1, slot t+4X
    w[1] = R2[B4];               // j = J+1 : region 2
    w[2] = R3[B4];               // j = J+2 : region 3
    #pragma unroll
    for (int m = 0; m < 16; ++m) {
        const int q = B4 + 1 + (m >> 2);   // slot offset of j = J+3+m
        const int rg = m & 3;              // region of j = J+3+m
        w[m + 3] = (rg == 0) ? R0[q] : (rg == 1) ? R1[q] : (rg == 2) ? R2[q] : R3[q];
        PT(pi0, w[m], accA);      // K = k0 + m
        PT(pi1, w[m + 1], accA);
        PT(pi2, w[m + 2], accB);
        PT(pi3, w[m + 3], accB);
    }

    // K=256 pairs (X==15, m==15) were counted at full weight from both
    // endpoints globally -> subtract half once per row. j = 4t+r+256.
    if (X == 15) {
        #define CORR(PI, W, ACC) do {                             \
            const float dx_ = (PI).x - (W).x;                     \
            const float dy_ = (PI).y - (W).y;                     \
            const float dz_ = (PI).z - (W).z;                     \
            const float r2_ = fmaf(dx_, dx_, fmaf(dy_, dy_, dz_ * dz_)); \
            const float i2_ = __builtin_amdgcn_rcpf(r2_);         \
            const float i6_ = i2_ * i2_ * i2_;                    \
            ACC -= 0.5f * i6_ * (i6_ - 1.0f);                     \
        } while (0)
        CORR(pi0, R0[64], accA);
        CORR(pi1, R1[64], accA);
        CORR(pi2, R2[64], accB);
        CORR(pi3, R3[64], accB);
        #undef CORR
    }
    #undef PT

    float pot = 4.0f * (accA + accB);

    #pragma unroll
    for (int off = 32; off; off >>= 1) pot += __shfl_down(pot, off, 64);

    // Harmonic COM restraint: X==0 threads (s==0, h==0) own particles
    // 4t..4t+3 exactly once -> waves 0,1 of the s==0 block.
    float sx = 0.0f, sy = 0.0f, sz = 0.0f, ssq = 0.0f;
    if (X == 0) {
        sx = pi0.x + pi1.x + pi2.x + pi3.x;
        sy = pi0.y + pi1.y + pi2.y + pi3.y;
        sz = pi0.z + pi1.z + pi2.z + pi3.z;
        ssq = pi0.x * pi0.x + pi0.y * pi0.y + pi0.z * pi0.z
            + pi1.x * pi1.x + pi1.y * pi1.y + pi1.z * pi1.z
            + pi2.x * pi2.x + pi2.y * pi2.y + pi2.z * pi2.z
            + pi3.x * pi3.x + pi3.y * pi3.y + pi3.z * pi3.z;
        #pragma unroll
        for (int off = 32; off; off >>= 1) {
            sx  += __shfl_down(sx,  off, 64);
            sy  += __shfl_down(sy,  off, 64);
            sz  += __shfl_down(sz,  off, 64);
            ssq += __shfl_down(ssq, off, 64);
        }
    }

    const int wave = tid >> 6;
    const int lane = tid & 63;
    if (lane == 0) {
        wred[wave] = pot;
        if (wave < 2 && s == 0) {
            wspr[wave][0] = sx; wspr[wave][1] = sy;
            wspr[wave][2] = sz; wspr[wave][3] = ssq;
        }
    }
    __syncthreads();

    if (tid == 0) {
        float P = 0.0f;
        #pragma unroll
        for (int w2 = 0; w2 < 16; ++w2) P += wred[w2];
        float res = P;
        if (s == 0) {
            const float SX = wspr[0][0] + wspr[1][0];
            const float SY = wspr[0][1] + wspr[1][1];
            const float SZ = wspr[0][2] + wspr[1][2];
            const float SS = wspr[0][3] + wspr[1][3];
            // 0.5*K_spring*sum(rel^2), K_spring=0.5 -> 0.25*(ssq - |S|^2/N)
            res += 0.25f * (SS - (SX * SX + SY * SY + SZ * SZ) * (1.0f / NPART));
        }

        // ---- fused finish: relaxed device-scope atomics + data-dep ordering ----
        // publish my partial at the coherent point
        const float oldp = __hip_atomic_exchange(
            &wsp[bid], res, __ATOMIC_RELAXED, __HIP_MEMORY_SCOPE_AGENT);
        // z = 0, but data-depends on oldp -> compiler emits s_waitcnt vmcnt(0)
        // before it: the publish has completed before the flag exchange issues.
        unsigned int z;
        asm volatile("v_and_b32 %0, 0, %1" : "=v"(z) : "v"(oldp));
        const unsigned int old = __hip_atomic_exchange(
            &done[b], MAGIC + z, __ATOMIC_RELAXED, __HIP_MEMORY_SCOPE_AGENT);
        if (old == MAGIC) {
            // sibling published-then-flagged (its own data-dep enforced that);
            // we observed its flag, so its partial is at the coherent point.
            unsigned int z2;
            asm volatile("v_and_b32 %0, 0, %1" : "=v"(z2) : "v"(old));
            const float other = __hip_atomic_load(
                &wsp[(bid ^ 1) + z2], __ATOMIC_RELAXED, __HIP_MEMORY_SCOPE_AGENT);
            out[b] = -(res + other);
            __hip_atomic_store(&done[b], 0u, __ATOMIC_RELAXED,
                               __HIP_MEMORY_SCOPE_AGENT);
        }
    }
}

extern "C" void kernel_launch(void* const* d_in, const int* in_sizes, int n_in,
                              void* d_out, int out_size, void* d_ws, size_t ws_size,
                              hipStream_t stream) {
    const float* x = (const float*)d_in[0];
    float* out = (float*)d_out;
    float* wsp = (float*)d_ws;                                  // 256 partials
    unsigned int* done = (unsigned int*)((char*)d_ws + 4096);   // 128 flags

    lj_fused<<<BATCH * 2, 1024, 0, stream>>>(x, out, wsp, done);
}

// Round 9
// 13.178 us; speedup vs baseline: 1.2060x; 1.2060x over previous
//
#include <hip/hip_runtime.h>

typedef float v2f __attribute__((ext_vector_type(2)));

#define NPART 512
#define BATCH 128

// Quad-split LDS layout (identical to the 13.0us R4 kernel): particle p ->
// region (p&3), slot (p>>2); regions 192 float4; mirror slot(p+512)=slot(p)+128.
// All window reads are stride-1 float4 across lanes (conflict-free ds_read_b128).
//
// grid = 256 = (batch b, half s); block = 1024 = (t in [0,128)) x (h in [0,8)).
// Thread (t,h,s): rows i = 4t+r (r=0..3), K in [16X+1, 16X+16], X = 8s+h.
// NEW vs R4: rows packed pairwise into v2f ({pi0,pi1},{pi2,pi3}); each window
// particle w[u] (j = J+u, J = 4t+16X+1) feeds one packed pair-term per row-pack
// (row r consumes w[u] at k = k0+u-r). Edges u=0,2,16,18 are scalar terms.
// Pair set is identical to R4's (validated, absmax 0.0).

__global__ __launch_bounds__(1024, 4) void lj_main(
    const float* __restrict__ x, float* __restrict__ ws) {
    const int bid = blockIdx.x;
    const int b = bid >> 1;
    const int s = bid & 1;
    const int tid = threadIdx.x;
    const int t = tid & 127;
    const int h = tid >> 7;

    __shared__ float4 sp[768];       // 4 regions x 192 float4 = 12 KB
    __shared__ float wred[16];
    __shared__ float wspr[2][4];

    // ---- stage 1536 floats (+768 mirror floats) into quad-split layout ----
    const float* xb = x + (size_t)b * (NPART * 3);
    float* spf = reinterpret_cast<float*>(sp);
    {
        const int idx = tid;                 // 0..1023
        const float v = xb[idx];
        const int p = idx / 3;
        const int c = idx - 3 * p;
        const int sl = (p & 3) * 192 + (p >> 2);
        spf[4 * sl + c] = v;
        if (p < 256) spf[4 * (sl + 128) + c] = v;   // mirror p+512
    }
    if (tid < 512) {
        const int idx = tid + 1024;          // 1024..1535 (p >= 341, no mirror)
        const float v = xb[idx];
        const int p = idx / 3;
        const int c = idx - 3 * p;
        const int sl = (p & 3) * 192 + (p >> 2);
        spf[4 * sl + c] = v;
    }
    __syncthreads();

    // region pointers at slot t
    const float4* R0 = sp + t;
    const float4* R1 = sp + 192 + t;
    const float4* R2 = sp + 384 + t;
    const float4* R3 = sp + 576 + t;

    const float4 pi0 = R0[0];   // particle 4t
    const float4 pi1 = R1[0];   // particle 4t+1
    const float4 pi2 = R2[0];   // particle 4t+2
    const float4 pi3 = R3[0];   // particle 4t+3

    const int X = 8 * s + h;     // 0..15 ; k0 = 16X+1 ; J = 4t + k0
    const int B4 = 4 * X;        // slot offset: slot(J+u) = t + B4 + ((1+u)>>2)

    // row-packed own coordinates (built once; zero per-iteration cost)
    const v2f p01x = {pi0.x, pi1.x}, p01y = {pi0.y, pi1.y}, p01z = {pi0.z, pi1.z};
    const v2f p23x = {pi2.x, pi3.x}, p23y = {pi2.y, pi3.y}, p23z = {pi2.z, pi3.z};
    const v2f vone = {1.0f, 1.0f};

    v2f acc01 = {0.f, 0.f}, acc23 = {0.f, 0.f};
    float accS = 0.0f;

    // window load: j = J+u -> region (1+u)&3, slot t + B4 + ((1+u)>>2)
    #define LOADW(u) \
        ((((1 + (u)) & 3) == 0) ? R0[B4 + ((1 + (u)) >> 2)] : \
         (((1 + (u)) & 3) == 1) ? R1[B4 + ((1 + (u)) >> 2)] : \
         (((1 + (u)) & 3) == 2) ? R2[B4 + ((1 + (u)) >> 2)] : \
                                  R3[B4 + ((1 + (u)) >> 2)])

    // packed pair-term: two rows vs one window particle; paired reciprocal
    #define PPT(PX, PY, PZ, WX, WY, WZ, ACC) do {                          \
        const v2f dx_ = (PX) - (WX);                                       \
        const v2f dy_ = (PY) - (WY);                                       \
        const v2f dz_ = (PZ) - (WZ);                                       \
        const v2f r2_ = __builtin_elementwise_fma(dx_, dx_,                \
                          __builtin_elementwise_fma(dy_, dy_, dz_ * dz_)); \
        const float pr_ = r2_.x * r2_.y;                                   \
        const float rt_ = __builtin_amdgcn_rcpf(pr_);                      \
        v2f i2_; i2_.x = r2_.y * rt_; i2_.y = r2_.x * rt_;                 \
        const v2f i6_ = i2_ * i2_ * i2_;                                   \
        ACC = __builtin_elementwise_fma(i6_, i6_ - vone, ACC);             \
    } while (0)

    // scalar pair-term (window edges)
    #define SPT(PI, W) do {                                                \
        const float dx_ = (PI).x - (W).x;                                  \
        const float dy_ = (PI).y - (W).y;                                  \
        const float dz_ = (PI).z - (W).z;                                  \
        const float r2_ = fmaf(dx_, dx_, fmaf(dy_, dy_, dz_ * dz_));       \
        const float i2_ = __builtin_amdgcn_rcpf(r2_);                      \
        const float i6_ = i2_ * i2_ * i2_;                                 \
        accS = fmaf(i6_, i6_ - 1.0f, accS);                                \
    } while (0)

    // u-step: load w[u] once, splat components once, feed all consumers.
    // Row0: u=0 scalar, u=1..15 packed01.  Row1: u=1..15 packed01, u=16 scalar.
    // Row2: u=2 scalar, u=3..17 packed23.  Row3: u=3..17 packed23, u=18 scalar.
    #define STEP(u) do {                                                   \
        const float4 W = LOADW(u);                                         \
        if ((u) == 0) SPT(pi0, W);                                         \
        if ((u) == 2) SPT(pi2, W);                                         \
        if ((u) == 16) SPT(pi1, W);                                        \
        if ((u) == 18) SPT(pi3, W);                                        \
        if ((u) >= 1 && (u) <= 15) {                                       \
            const v2f wx = {W.x, W.x}, wy = {W.y, W.y}, wz = {W.z, W.z};   \
            PPT(p01x, p01y, p01z, wx, wy, wz, acc01);                      \
            if ((u) >= 3) PPT(p23x, p23y, p23z, wx, wy, wz, acc23);        \
        } else if ((u) >= 3 && (u) <= 17) {                                \
            const v2f wx = {W.x, W.x}, wy = {W.y, W.y}, wz = {W.z, W.z};   \
            PPT(p23x, p23y, p23z, wx, wy, wz, acc23);                      \
        }                                                                  \
    } while (0)

    STEP(0);  STEP(1);  STEP(2);  STEP(3);  STEP(4);  STEP(5);  STEP(6);
    STEP(7);  STEP(8);  STEP(9);  STEP(10); STEP(11); STEP(12); STEP(13);
    STEP(14); STEP(15); STEP(16); STEP(17); STEP(18);

    #undef STEP
    #undef LOADW
    #undef PPT

    // K=256 pairs (X==15, k=k0+15) were counted at full weight from both
    // endpoints globally -> subtract half once per row. j = 4t+r+256.
    if (X == 15) {
        #define CORR(PI, W) do {                                           \
            const float dx_ = (PI).x - (W).x;                              \
            const float dy_ = (PI).y - (W).y;                              \
            const float dz_ = (PI).z - (W).z;                              \
            const float r2_ = fmaf(dx_, dx_, fmaf(dy_, dy_, dz_ * dz_));   \
            const float i2_ = __builtin_amdgcn_rcpf(r2_);                  \
            const float i6_ = i2_ * i2_ * i2_;                             \
            accS -= 0.5f * i6_ * (i6_ - 1.0f);                             \
        } while (0)
        CORR(pi0, R0[64]);
        CORR(pi1, R1[64]);
        CORR(pi2, R2[64]);
        CORR(pi3, R3[64]);
        #undef CORR
    }
    #undef SPT

    float pot = 4.0f * (acc01.x + acc01.y + acc23.x + acc23.y + accS);

    #pragma unroll
    for (int off = 32; off; off >>= 1) pot += __shfl_down(pot, off, 64);

    // Harmonic COM restraint: X==0 threads own particles 4t..4t+3 exactly once.
    float sx = 0.0f, sy = 0.0f, sz = 0.0f, ssq = 0.0f;
    if (X == 0) {
        sx = pi0.x + pi1.x + pi2.x + pi3.x;
        sy = pi0.y + pi1.y + pi2.y + pi3.y;
        sz = pi0.z + pi1.z + pi2.z + pi3.z;
        ssq = pi0.x * pi0.x + pi0.y * pi0.y + pi0.z * pi0.z
            + pi1.x * pi1.x + pi1.y * pi1.y + pi1.z * pi1.z
            + pi2.x * pi2.x + pi2.y * pi2.y + pi2.z * pi2.z
            + pi3.x * pi3.x + pi3.y * pi3.y + pi3.z * pi3.z;
        #pragma unroll
        for (int off = 32; off; off >>= 1) {
            sx  += __shfl_down(sx,  off, 64);
            sy  += __shfl_down(sy,  off, 64);
            sz  += __shfl_down(sz,  off, 64);
            ssq += __shfl_down(ssq, off, 64);
        }
    }

    const int wave = tid >> 6;
    const int lane = tid & 63;
    if (lane == 0) {
        wred[wave] = pot;
        if (wave < 2 && s == 0) {
            wspr[wave][0] = sx; wspr[wave][1] = sy;
            wspr[wave][2] = sz; wspr[wave][3] = ssq;
        }
    }
    __syncthreads();

    if (tid == 0) {
        float P = 0.0f;
        #pragma unroll
        for (int w2 = 0; w2 < 16; ++w2) P += wred[w2];
        float res = P;
        if (s == 0) {
            const float SX = wspr[0][0] + wspr[1][0];
            const float SY = wspr[0][1] + wspr[1][1];
            const float SZ = wspr[0][2] + wspr[1][2];
            const float SS = wspr[0][3] + wspr[1][3];
            // 0.5*K_spring*sum(rel^2), K_spring=0.5 -> 0.25*(ssq - |S|^2/N)
            res += 0.25f * (SS - (SX * SX + SY * SY + SZ * SZ) * (1.0f / NPART));
        }
        ws[bid] = res;
    }
}

__global__ void lj_combine(const float* __restrict__ ws,
                           float* __restrict__ out) {
    const int t = threadIdx.x;
    if (t < BATCH) out[t] = -(ws[2 * t] + ws[2 * t + 1]);
}

extern "C" void kernel_launch(void* const* d_in, const int* in_sizes, int n_in,
                              void* d_out, int out_size, void* d_ws, size_t ws_size,
                              hipStream_t stream) {
    const float* x = (const float*)d_in[0];
    float* out = (float*)d_out;
    float* pw = (float*)d_ws;   // 256 partials

    lj_main<<<BATCH * 2, 1024, 0, stream>>>(x, pw);
    lj_combine<<<1, 128, 0, stream>>>(pw, out);
}

// Round 10
// 13.129 us; speedup vs baseline: 1.2105x; 1.0037x over previous
//
#include <hip/hip_runtime.h>

#define NPART 512
#define BATCH 128

// ===== Measured-best kernel (R4 structure, 13.0 us) =====
//
// Quad-split LDS layout: particle p -> region (p&3), slot (p>>2).
// Regions are 192 float4 each (particles mirrored to p<768: slot(p+512)=slot(p)+128).
// Window reads are stride-1 float4 across lanes (conflict-free ds_read_b128),
// with compile-time immediate offsets under full unroll.
//
// grid = 256 blocks = (batch b, half s). block = 1024 threads = (t in [0,128)) x (h in [0,8)).
// Thread (t,h,s): rows i = 4t+r (r=0..3), K in [16X+1, 16X+16], X = 8s+h in [0,16).
// Each unordered pair with circular distance d<256 counted once; d=256 counted
// twice at full weight, corrected by -0.5 in the X==15 threads.
//
// Session findings (measured):
//  - Two-kernel structure beats all fusion variants: agent-scope rel/acq
//    handshake +6us (L2 wb/inv sweeps), relaxed-atomic handshake +3us,
//    single-kernel (128 blocks) +4.7us (half CU coverage).
//  - Parity/quad-split LDS keeps all ds_read_b128 conflict-free.
//  - v2f packing of the inner loop is perf-neutral (kernel not VALU-bound
//    at this scale; total dominated by ~10us fixed replay overhead).

__global__ __launch_bounds__(1024, 4) void lj_main(
    const float* __restrict__ x, float* __restrict__ ws) {
    const int bid = blockIdx.x;
    const int b = bid >> 1;
    const int s = bid & 1;
    const int tid = threadIdx.x;
    const int t = tid & 127;
    const int h = tid >> 7;

    __shared__ float4 sp[768];       // 4 regions x 192 float4 = 12 KB
    __shared__ float wred[16];
    __shared__ float wspr[2][4];

    // ---- stage 1536 floats (+768 mirror floats) into quad-split layout ----
    const float* xb = x + (size_t)b * (NPART * 3);
    float* spf = reinterpret_cast<float*>(sp);
    {
        const int idx = tid;                 // 0..1023
        const float v = xb[idx];
        const int p = idx / 3;
        const int c = idx - 3 * p;
        const int sl = (p & 3) * 192 + (p >> 2);
        spf[4 * sl + c] = v;
        if (p < 256) spf[4 * (sl + 128) + c] = v;   // mirror p+512
    }
    if (tid < 512) {
        const int idx = tid + 1024;          // 1024..1535 (p >= 341, no mirror)
        const float v = xb[idx];
        const int p = idx / 3;
        const int c = idx - 3 * p;
        const int sl = (p & 3) * 192 + (p >> 2);
        spf[4 * sl + c] = v;
    }
    __syncthreads();

    // region pointers at slot t
    const float4* R0 = sp + t;
    const float4* R1 = sp + 192 + t;
    const float4* R2 = sp + 384 + t;
    const float4* R3 = sp + 576 + t;

    const float4 pi0 = R0[0];   // particle 4t
    const float4 pi1 = R1[0];   // particle 4t+1
    const float4 pi2 = R2[0];   // particle 4t+2
    const float4 pi3 = R3[0];   // particle 4t+3

    const int X = 8 * s + h;     // 0..15 ; k0 = 16X+1 ; J = 4t + k0
    const int B4 = 4 * X;        // window slot offset (J>>2 = t + 4X)

    float accA = 0.0f, accB = 0.0f;

    // acc += i6*(i6-1) ; pot = 4*acc
    #define PT(PI, W, ACC) do {                                   \
        const float dx_ = (PI).x - (W).x;                         \
        const float dy_ = (PI).y - (W).y;                         \
        const float dz_ = (PI).z - (W).z;                         \
        const float r2_ = fmaf(dx_, dx_, fmaf(dy_, dy_, dz_ * dz_)); \
        const float i2_ = __builtin_amdgcn_rcpf(r2_);             \
        const float i6_ = i2_ * i2_ * i2_;                        \
        ACC = fmaf(i6_, i6_ - 1.0f, ACC);                         \
    } while (0)

    // sliding window w[m] holds particle j = J + m  (J = 4t + 16X + 1)
    float4 w[19];
    w[0] = R1[B4];               // j = J   : region 1, slot t+4X
    w[1] = R2[B4];               // j = J+1 : region 2
    w[2] = R3[B4];               // j = J+2 : region 3
    #pragma unroll
    for (int m = 0; m < 16; ++m) {
        const int q = B4 + 1 + (m >> 2);   // slot offset of j = J+3+m
        const int rg = m & 3;              // region of j = J+3+m
        w[m + 3] = (rg == 0) ? R0[q] : (rg == 1) ? R1[q] : (rg == 2) ? R2[q] : R3[q];
        PT(pi0, w[m], accA);      // K = k0 + m
        PT(pi1, w[m + 1], accA);
        PT(pi2, w[m + 2], accB);
        PT(pi3, w[m + 3], accB);
    }

    // K=256 pairs (X==15, m==15) were counted at full weight from both
    // endpoints globally -> subtract half once per row. j = 4t+r+256.
    if (X == 15) {
        #define CORR(PI, W, ACC) do {                             \
            const float dx_ = (PI).x - (W).x;                     \
            const float dy_ = (PI).y - (W).y;                     \
            const float dz_ = (PI).z - (W).z;                     \
            const float r2_ = fmaf(dx_, dx_, fmaf(dy_, dy_, dz_ * dz_)); \
            const float i2_ = __builtin_amdgcn_rcpf(r2_);         \
            const float i6_ = i2_ * i2_ * i2_;                    \
            ACC -= 0.5f * i6_ * (i6_ - 1.0f);                     \
        } while (0)
        CORR(pi0, R0[64], accA);
        CORR(pi1, R1[64], accA);
        CORR(pi2, R2[64], accB);
        CORR(pi3, R3[64], accB);
        #undef CORR
    }
    #undef PT

    float pot = 4.0f * (accA + accB);

    #pragma unroll
    for (int off = 32; off; off >>= 1) pot += __shfl_down(pot, off, 64);

    // Harmonic COM restraint: X==0 threads (s==0, h==0) own particles
    // 4t..4t+3 exactly once -> waves 0,1 of the s==0 block.
    float sx = 0.0f, sy = 0.0f, sz = 0.0f, ssq = 0.0f;
    if (X == 0) {
        sx = pi0.x + pi1.x + pi2.x + pi3.x;
        sy = pi0.y + pi1.y + pi2.y + pi3.y;
        sz = pi0.z + pi1.z + pi2.z + pi3.z;
        ssq = pi0.x * pi0.x + pi0.y * pi0.y + pi0.z * pi0.z
            + pi1.x * pi1.x + pi1.y * pi1.y + pi1.z * pi1.z
            + pi2.x * pi2.x + pi2.y * pi2.y + pi2.z * pi2.z
            + pi3.x * pi3.x + pi3.y * pi3.y + pi3.z * pi3.z;
        #pragma unroll
        for (int off = 32; off; off >>= 1) {
            sx  += __shfl_down(sx,  off, 64);
            sy  += __shfl_down(sy,  off, 64);
            sz  += __shfl_down(sz,  off, 64);
            ssq += __shfl_down(ssq, off, 64);
        }
    }

    const int wave = tid >> 6;
    const int lane = tid & 63;
    if (lane == 0) {
        wred[wave] = pot;
        if (wave < 2 && s == 0) {
            wspr[wave][0] = sx; wspr[wave][1] = sy;
            wspr[wave][2] = sz; wspr[wave][3] = ssq;
        }
    }
    __syncthreads();

    if (tid == 0) {
        float P = 0.0f;
        #pragma unroll
        for (int w2 = 0; w2 < 16; ++w2) P += wred[w2];
        float res = P;
        if (s == 0) {
            const float SX = wspr[0][0] + wspr[1][0];
            const float SY = wspr[0][1] + wspr[1][1];
            const float SZ = wspr[0][2] + wspr[1][2];
            const float SS = wspr[0][3] + wspr[1][3];
            // 0.5*K_spring*sum(rel^2), K_spring=0.5 -> 0.25*(ssq - |S|^2/N)
            res += 0.25f * (SS - (SX * SX + SY * SY + SZ * SZ) * (1.0f / NPART));
        }
        ws[bid] = res;
    }
}

__global__ void lj_combine(const float* __restrict__ ws,
                           float* __restrict__ out) {
    const int t = threadIdx.x;
    if (t < BATCH) out[t] = -(ws[2 * t] + ws[2 * t + 1]);
}

extern "C" void kernel_launch(void* const* d_in, const int* in_sizes, int n_in,
                              void* d_out, int out_size, void* d_ws, size_t ws_size,
                              hipStream_t stream) {
    const float* x = (const float*)d_in[0];
    float* out = (float*)d_out;
    float* pw = (float*)d_ws;   // 256 partials

    lj_main<<<BATCH * 2, 1024, 0, stream>>>(x, pw);
    lj_combine<<<1, 128, 0, stream>>>(pw, out);
}